// Round 16
// baseline (126.666 us; speedup 1.0000x reference)
//
#include <hip/hip_runtime.h>

typedef unsigned char u8;
typedef float fp32x4 __attribute__((ext_vector_type(4)));
typedef long lx2 __attribute__((ext_vector_type(2)));

#define BS 4096
#define NROW 8192
#define D 512
#define NB64 128                      // 64-row bands
#define NT64 (NB64 * (NB64 + 1) / 2)  // 8256 upper-triangle 64x64 wave-tiles
#define NPBLK 512                     // R11-verified best: 2 blocks/CU
#define NTHR 256
#define NSTAT 8192                    // static tiles: 2048 waves x 4 exactly
// An = z_hat * sqrt(10*log2(e)) -> acc = sim*10*log2e -> exp(sim*10)=2^acc.
#define SCALE 3.79828286f
#define LN2 0.69314718f

// Packed An layout (verified R2/R4/R11): per (rowgroup g, k-pair p) a wave's
// fragment reads are one contiguous 1KB block (coalesced from L2).
// 8-byte chunk L = k>>3 of row r:
//   off(r, L) = (r>>4)*8192 + (L>>3)*1024 + (r&15)*64
//             + (((L&3) ^ ((r&15)>>2)) << 4) + (((L>>2)&1) << 3)
// Fragment for lane (fr=l&15, h=l>>4), rowgroup g, k-pair p is the 16 B at
//   g*8192 + p*1024 + fr*64 + ((h^(fr>>2))&3)*16   (one lx2 = ks 2p, 2p+1)

// Wave-per-row normalize -> fp8 e4m3 (scaled), packed layout.
// Also zeroes den + counters (ws is re-poisoned before every launch).
__global__ __launch_bounds__(256) void normalize_k(
    const float* __restrict__ zi, const float* __restrict__ zj,
    u8* __restrict__ An, float* __restrict__ den, float* __restrict__ posAcc,
    int* __restrict__ ctrs) {
  const int lane = threadIdx.x & 63;
  const int wave = threadIdx.x >> 6;
  const int r = blockIdx.x * 4 + wave;
  const float* src = (r < BS) ? (zi + (size_t)r * D) : (zj + (size_t)(r - BS) * D);
  const float4 v0 = ((const float4*)src)[lane * 2];
  const float4 v1 = ((const float4*)src)[lane * 2 + 1];
  float ss = v0.x * v0.x + v0.y * v0.y + v0.z * v0.z + v0.w * v0.w +
             v1.x * v1.x + v1.y * v1.y + v1.z * v1.z + v1.w * v1.w;
#pragma unroll
  for (int off = 1; off < 64; off <<= 1) ss += __shfl_xor(ss, off);
  const float inv = SCALE / fmaxf(sqrtf(ss), 1e-8f);
  int lo = __builtin_amdgcn_cvt_pk_fp8_f32(v0.x * inv, v0.y * inv, 0, false);
  lo = __builtin_amdgcn_cvt_pk_fp8_f32(v0.z * inv, v0.w * inv, lo, true);
  int hi = __builtin_amdgcn_cvt_pk_fp8_f32(v1.x * inv, v1.y * inv, 0, false);
  hi = __builtin_amdgcn_cvt_pk_fp8_f32(v1.z * inv, v1.w * inv, hi, true);
  // lane holds chunk L = lane (k = 8*lane .. +8)
  const int r16 = r & 15;
  const int off = ((r >> 4) << 13) + ((lane >> 3) << 10) + (r16 << 6) +
                  ((((lane & 3) ^ (r16 >> 2)) & 3) << 4) + (((lane >> 2) & 1) << 3);
  *(int2*)(An + off) = make_int2(lo, hi);
  if (lane == 0) den[r] = 0.0f;
  if (blockIdx.x == 0) {
    if (threadIdx.x == 0) posAcc[0] = 0.0f;
    for (int z = threadIdx.x; z < 288; z += 256) ctrs[z] = 0;
  }
}

// Wave-owned 64x64 triangle tiles (R11 core, best measured: 52us).
// ZERO LDS/barriers in the hot loop; A band in VGPRs; B streamed from L2
// with in-tile p+1 prefetch. R16 changes vs R11 (single-lever discipline
// after R15's setprio/persistent-bb regression, FETCH 14->21.5 MB):
//  - load balance: static 4 tiles/wave ([0,8192)); last 64 tiles grabbed
//    dynamically (R11's 64 five-tile waves set the wall: 5/4.03 = +24%).
//  - positive-pair work hoisted behind wave-uniform bj==bi+64 (R12-R15).
// NO setprio (m190 + R15: hurts GEMM L2 locality). No cross-tile bb.
__global__ __launch_bounds__(NTHR, 2) void gemm_expsum(
    const u8* __restrict__ An, float* __restrict__ den,
    float* __restrict__ posAcc, int* __restrict__ ctrs,
    float* __restrict__ out) {
  __shared__ float redbuf[4];
  __shared__ int lastFlag;

  const int tid = threadIdx.x;
  const int lane = tid & 63;
  const int wave = tid >> 6;
  const int fr = lane & 15;
  const int h = lane >> 4;
  const int fbase = fr * 64 + ((h ^ (fr >> 2)) & 3) * 16;
  const u8* gaBase = An + fbase;

  // XCD-contiguous chunking: blocks on one XCD cover a contiguous tile range
  const int bid = (int)((blockIdx.x & 7) * (NPBLK / 8) + (blockIdx.x >> 3));
  const int wid = bid * 4 + wave;

  lx2 aF[4][8];
  auto loadA = [&](int band) {
#pragma unroll
    for (int i = 0; i < 4; ++i) {
      const u8* ga = gaBase + (size_t)(band * 4 + i) * 8192;
#pragma unroll
      for (int p = 0; p < 8; ++p) aF[i][p] = *(const lx2*)(ga + p * 1024);
    }
  };

  auto doTile = [&](int bi, int bj) {
    const bool diag = (bi == bj);
    fp32x4 acc[4][4] = {};

    if (diag) {
      // B == A: pure-register K loop
#pragma unroll
      for (int p = 0; p < 8; ++p) {
#pragma unroll
        for (int i = 0; i < 4; ++i)
#pragma unroll
          for (int j = 0; j < 4; ++j)
            acc[i][j] = __builtin_amdgcn_mfma_f32_16x16x32_fp8_fp8(
                aF[i][p][0], aF[j][p][0], acc[i][j], 0, 0, 0);
#pragma unroll
        for (int i = 0; i < 4; ++i)
#pragma unroll
          for (int j = 0; j < 4; ++j)
            acc[i][j] = __builtin_amdgcn_mfma_f32_16x16x32_fp8_fp8(
                aF[i][p][1], aF[j][p][1], acc[i][j], 0, 0, 0);
      }
    } else {
      const u8* gb = gaBase + (size_t)bj * 32768;
      lx2 bb[2][4];
#pragma unroll
      for (int j = 0; j < 4; ++j) bb[0][j] = *(const lx2*)(gb + j * 8192);
#pragma unroll
      for (int p = 0; p < 8; ++p) {
        if (p < 7) {
#pragma unroll
          for (int j = 0; j < 4; ++j)
            bb[(p + 1) & 1][j] = *(const lx2*)(gb + j * 8192 + (p + 1) * 1024);
        }
#pragma unroll
        for (int i = 0; i < 4; ++i)
#pragma unroll
          for (int j = 0; j < 4; ++j)
            acc[i][j] = __builtin_amdgcn_mfma_f32_16x16x32_fp8_fp8(
                aF[i][p][0], bb[p & 1][j][0], acc[i][j], 0, 0, 0);
#pragma unroll
        for (int i = 0; i < 4; ++i)
#pragma unroll
          for (int j = 0; j < 4; ++j)
            acc[i][j] = __builtin_amdgcn_mfma_f32_16x16x32_fp8_fp8(
                aF[i][p][1], bb[p & 1][j][1], acc[i][j], 0, 0, 0);
      }
    }

    // Epilogue. acc = sim*10*log2e -> e = 2^acc. C/D layout:
    // col = lane&15, row = (lane>>4)*4 + reg.
    const int rowBase = bi * 64;
    const int colBase = bj * 64;
    const int rq = h * 4;
    float colAcc[4] = {0.0f, 0.0f, 0.0f, 0.0f};
#pragma unroll
    for (int i = 0; i < 4; ++i) {
      const int rbase = rowBase + i * 16 + rq;
      float rs[4] = {0.0f, 0.0f, 0.0f, 0.0f};
#pragma unroll
      for (int j = 0; j < 4; ++j) {
        fp32x4 v = acc[i][j];
#pragma unroll
        for (int rg = 0; rg < 4; ++rg) {
          float e = __builtin_amdgcn_exp2f(v[rg]);
          if (diag && (rbase + rg) == (colBase + j * 16 + fr))
            e = 0.0f;  // exclude exact diagonal
          rs[rg] += e;
          colAcc[j] += e;
        }
      }
#pragma unroll
      for (int rg = 0; rg < 4; ++rg) {
        float s = rs[rg];
        s += __shfl_xor(s, 1);
        s += __shfl_xor(s, 2);
        s += __shfl_xor(s, 4);
        s += __shfl_xor(s, 8);
        if (fr == 0) atomicAdd(&den[rbase + rg], s);
      }
    }
    if (!diag) {
#pragma unroll
      for (int j = 0; j < 4; ++j) {
        float c = colAcc[j];
        c += __shfl_xor(c, 16);
        c += __shfl_xor(c, 32);
        if (h == 0) atomicAdd(&den[colBase + j * 16 + fr], c);
      }
    }

    // positives exist ONLY when bj == bi + BS/64 (64 of 8256 tiles)
    if (bj == bi + (BS / 64)) {
      float posPart = 0.0f;
#pragma unroll
      for (int i = 0; i < 4; ++i)
#pragma unroll
        for (int j = 0; j < 4; ++j) {
          fp32x4 v = acc[i][j];
#pragma unroll
          for (int rg = 0; rg < 4; ++rg)
            if (j * 16 + fr == i * 16 + rq + rg) posPart += v[rg] * LN2;
        }
      posPart += __shfl_xor(posPart, 1);
      posPart += __shfl_xor(posPart, 2);
      posPart += __shfl_xor(posPart, 4);
      posPart += __shfl_xor(posPart, 8);
      posPart += __shfl_xor(posPart, 16);
      posPart += __shfl_xor(posPart, 32);
      if (lane == 0) atomicAdd(posAcc, posPart);  // upper copy; doubled later
    }
  };

  // ---- static phase: exactly 4 contiguous tiles per wave ----
  {
    int rem = wid * 4, bi = 0;
    while (rem >= NB64 - bi) { rem -= NB64 - bi; ++bi; }
    int bj = bi + rem;
    loadA(bi);
#pragma unroll
    for (int s = 0; s < 4; ++s) {
      doTile(bi, bj);
      ++bj;
      if (bj == NB64) {
        ++bi;
        bj = bi;
        if (s < 3) loadA(bi);
      }
    }
  }

  // ---- dynamic phase: first-finishers steal the last 64 tiles ----
  for (;;) {
    int g;
    if (lane == 0)
      g = NSTAT + __hip_atomic_fetch_add(&ctrs[8], 1, __ATOMIC_RELAXED,
                                         __HIP_MEMORY_SCOPE_AGENT);
    g = __shfl(g, 0);
    if (g >= NT64) break;
    int rem = g, bi = 0;
    while (rem >= NB64 - bi) { rem -= NB64 - bi; ++bi; }
    loadA(bi);
    doTile(bi, bi + rem);
  }

  // ---- fence-free tail (no buffer_wbl2/inv: that was +15-19us, R8->R9) --
  // each wave drains its own atomics, THEN the block barrier, THEN publish.
  asm volatile("s_waitcnt vmcnt(0)" ::: "memory");
  __syncthreads();
  if (tid == 0) {
    // hierarchical publish: 8 padded group counters then a master counter
    const int g = (int)(blockIdx.x & 7);
    int last = 0;
    if (__hip_atomic_fetch_add(&ctrs[32 + g * 32], 1, __ATOMIC_RELAXED,
                               __HIP_MEMORY_SCOPE_AGENT) == NPBLK / 8 - 1)
      last = (__hip_atomic_fetch_add(&ctrs[0], 1, __ATOMIC_RELAXED,
                                     __HIP_MEMORY_SCOPE_AGENT) == 7);
    lastFlag = last;
  }
  __syncthreads();
  if (lastFlag) {
    // batched: all 32 per-thread agent-scope loads in flight before use
    float v[32];
#pragma unroll
    for (int io = 0; io < 32; ++io)
      v[io] = __hip_atomic_load(&den[tid + io * NTHR], __ATOMIC_RELAXED,
                                __HIP_MEMORY_SCOPE_AGENT);
    float s = 0.0f;
#pragma unroll
    for (int io = 0; io < 32; ++io)
      s += __builtin_amdgcn_logf(v[io]);  // log2; *ln2 once at the end
#pragma unroll
    for (int off = 1; off < 64; off <<= 1) s += __shfl_xor(s, off);
    if (lane == 0) redbuf[wave] = s;
    __syncthreads();
    if (tid == 0) {
      const float tot =
          (redbuf[0] + redbuf[1] + redbuf[2] + redbuf[3]) * LN2;  // -> ln
      const float pos = __hip_atomic_load(posAcc, __ATOMIC_RELAXED,
                                          __HIP_MEMORY_SCOPE_AGENT);
      // each unordered positive pair was counted once -> double it
      out[0] = (tot - 2.0f * pos) * (1.0f / (float)NROW);
    }
  }
}

extern "C" void kernel_launch(void* const* d_in, const int* in_sizes, int n_in,
                              void* d_out, int out_size, void* d_ws, size_t ws_size,
                              hipStream_t stream) {
  const float* zi = (const float*)d_in[0];
  const float* zj = (const float*)d_in[1];
  float* out = (float*)d_out;

  u8* An = (u8*)d_ws;                                      // 4 MB packed fp8
  float* den = (float*)((char*)d_ws + (size_t)NROW * D);   // 8192 fp32
  float* posAcc = den + NROW;                              // 1 fp32
  int* ctrs = (int*)(posAcc + 1);                          // 288 ints (padded)

  normalize_k<<<NROW / 4, 256, 0, stream>>>(zi, zj, An, den, posAcc, ctrs);
  gemm_expsum<<<NPBLK, NTHR, 0, stream>>>(An, den, posAcc, ctrs, out);
}

// Round 17
// 113.597 us; speedup vs baseline: 1.1151x; 1.1151x over previous
//
#include <hip/hip_runtime.h>

typedef unsigned char u8;
typedef float fp32x4 __attribute__((ext_vector_type(4)));
typedef long lx2 __attribute__((ext_vector_type(2)));

#define BS 4096
#define NROW 8192
#define D 512
#define NB64 128                      // 64-row bands
#define NT64 (NB64 * (NB64 + 1) / 2)  // 8256 upper-triangle 64x64 wave-tiles
#define NPBLK 512                     // R11-verified best: 2 blocks/CU
#define NTHR 256
// An = z_hat * sqrt(10*log2(e)) -> acc = sim*10*log2e -> exp(sim*10)=2^acc.
#define SCALE 3.79828286f
#define LN2 0.69314718f

// Packed An layout (verified R2/R4/R11): per (rowgroup g, k-pair p) a wave's
// fragment reads are one contiguous 1KB block (coalesced from L2).
// 8-byte chunk L = k>>3 of row r:
//   off(r, L) = (r>>4)*8192 + (L>>3)*1024 + (r&15)*64
//             + (((L&3) ^ ((r&15)>>2)) << 4) + (((L>>2)&1) << 3)
// Fragment for lane (fr=l&15, h=l>>4), rowgroup g, k-pair p is the 16 B at
//   g*8192 + p*1024 + fr*64 + ((h^(fr>>2))&3)*16   (one lx2 = ks 2p, 2p+1)

// Wave-per-row normalize -> fp8 e4m3 (scaled), packed layout.
// Also zeroes den + counters (ws is re-poisoned before every launch).
__global__ __launch_bounds__(256) void normalize_k(
    const float* __restrict__ zi, const float* __restrict__ zj,
    u8* __restrict__ An, float* __restrict__ den, float* __restrict__ posAcc,
    int* __restrict__ ctrs) {
  const int lane = threadIdx.x & 63;
  const int wave = threadIdx.x >> 6;
  const int r = blockIdx.x * 4 + wave;
  const float* src = (r < BS) ? (zi + (size_t)r * D) : (zj + (size_t)(r - BS) * D);
  const float4 v0 = ((const float4*)src)[lane * 2];
  const float4 v1 = ((const float4*)src)[lane * 2 + 1];
  float ss = v0.x * v0.x + v0.y * v0.y + v0.z * v0.z + v0.w * v0.w +
             v1.x * v1.x + v1.y * v1.y + v1.z * v1.z + v1.w * v1.w;
#pragma unroll
  for (int off = 1; off < 64; off <<= 1) ss += __shfl_xor(ss, off);
  const float inv = SCALE / fmaxf(sqrtf(ss), 1e-8f);
  int lo = __builtin_amdgcn_cvt_pk_fp8_f32(v0.x * inv, v0.y * inv, 0, false);
  lo = __builtin_amdgcn_cvt_pk_fp8_f32(v0.z * inv, v0.w * inv, lo, true);
  int hi = __builtin_amdgcn_cvt_pk_fp8_f32(v1.x * inv, v1.y * inv, 0, false);
  hi = __builtin_amdgcn_cvt_pk_fp8_f32(v1.z * inv, v1.w * inv, hi, true);
  // lane holds chunk L = lane (k = 8*lane .. +8)
  const int r16 = r & 15;
  const int off = ((r >> 4) << 13) + ((lane >> 3) << 10) + (r16 << 6) +
                  ((((lane & 3) ^ (r16 >> 2)) & 3) << 4) + (((lane >> 2) & 1) << 3);
  *(int2*)(An + off) = make_int2(lo, hi);
  if (lane == 0) den[r] = 0.0f;
  if (blockIdx.x == 0) {
    if (threadIdx.x == 0) posAcc[0] = 0.0f;
    for (int z = threadIdx.x; z < 288; z += 256) ctrs[z] = 0;
  }
}

// Wave-owned 64x64 triangle tiles (R11 core = best measured 52us).
// ZERO LDS/barriers in the hot loop; A band in VGPRs (aF[4][8]); B streamed
// from L2. R17 single mechanism change vs R11: B prefetch depth 1 -> 2
// (bb[3][4] rotation, issue p+2 before p's MFMAs). FETCH=3.5x An shows ~1/3
// of B p-blocks miss to HBM (~900cy); depth-1 cover (~600-1200cy) was
// marginal, depth-2 (~1300-2500cy) covers fully. +16 VGPR (~190 < 256: same
// 2 waves/SIMD). Also keeps the R16-verified positive-pair hoist.
// NO steal loop / NO unrolled tile loop (R16: I-cache bloat, +14us).
// NO setprio (m190 + R15). launch_bounds stays (256,2) (R12: (,4) = spill).
__global__ __launch_bounds__(NTHR, 2) void gemm_expsum(
    const u8* __restrict__ An, float* __restrict__ den,
    float* __restrict__ posAcc, int* __restrict__ ctrs,
    float* __restrict__ out) {
  __shared__ float redbuf[4];
  __shared__ int lastFlag;

  const int tid = threadIdx.x;
  const int lane = tid & 63;
  const int wave = tid >> 6;
  const int fr = lane & 15;
  const int h = lane >> 4;
  const int fbase = fr * 64 + ((h ^ (fr >> 2)) & 3) * 16;
  const u8* gaBase = An + fbase;

  // XCD-contiguous chunking: blocks on one XCD cover a contiguous tile range
  const int bid = (int)((blockIdx.x & 7) * (NPBLK / 8) + (blockIdx.x >> 3));
  const int wid = bid * 4 + wave;
  const int t0 = (int)(((long)wid * NT64) >> 11);
  const int t1 = (int)(((long)(wid + 1) * NT64) >> 11);

  int rem = t0, bi = 0;
  while (rem >= NB64 - bi) { rem -= NB64 - bi; ++bi; }
  int bj = bi + rem;

  lx2 aF[4][8];
  auto loadA = [&](int band) {
#pragma unroll
    for (int i = 0; i < 4; ++i) {
      const u8* ga = gaBase + (size_t)(band * 4 + i) * 8192;
#pragma unroll
      for (int p = 0; p < 8; ++p) aF[i][p] = *(const lx2*)(ga + p * 1024);
    }
  };
  loadA(bi);

  for (int t = t0; t < t1; ++t) {
    const bool diag = (bi == bj);
    fp32x4 acc[4][4] = {};

    if (diag) {
      // B == A: pure-register K loop
#pragma unroll
      for (int p = 0; p < 8; ++p) {
#pragma unroll
        for (int i = 0; i < 4; ++i)
#pragma unroll
          for (int j = 0; j < 4; ++j)
            acc[i][j] = __builtin_amdgcn_mfma_f32_16x16x32_fp8_fp8(
                aF[i][p][0], aF[j][p][0], acc[i][j], 0, 0, 0);
#pragma unroll
        for (int i = 0; i < 4; ++i)
#pragma unroll
          for (int j = 0; j < 4; ++j)
            acc[i][j] = __builtin_amdgcn_mfma_f32_16x16x32_fp8_fp8(
                aF[i][p][1], aF[j][p][1], acc[i][j], 0, 0, 0);
      }
    } else {
      const u8* gb = gaBase + (size_t)bj * 32768;
      lx2 bb[3][4];  // depth-2 rotation: p uses bb[p%3], issue p+2
#pragma unroll
      for (int j = 0; j < 4; ++j) bb[0][j] = *(const lx2*)(gb + j * 8192);
#pragma unroll
      for (int j = 0; j < 4; ++j)
        bb[1][j] = *(const lx2*)(gb + j * 8192 + 1024);
#pragma unroll
      for (int p = 0; p < 8; ++p) {
        if (p < 6) {
#pragma unroll
          for (int j = 0; j < 4; ++j)
            bb[(p + 2) % 3][j] = *(const lx2*)(gb + j * 8192 + (p + 2) * 1024);
        }
#pragma unroll
        for (int i = 0; i < 4; ++i)
#pragma unroll
          for (int j = 0; j < 4; ++j)
            acc[i][j] = __builtin_amdgcn_mfma_f32_16x16x32_fp8_fp8(
                aF[i][p][0], bb[p % 3][j][0], acc[i][j], 0, 0, 0);
#pragma unroll
        for (int i = 0; i < 4; ++i)
#pragma unroll
          for (int j = 0; j < 4; ++j)
            acc[i][j] = __builtin_amdgcn_mfma_f32_16x16x32_fp8_fp8(
                aF[i][p][1], bb[p % 3][j][1], acc[i][j], 0, 0, 0);
      }
    }

    // Epilogue. acc = sim*10*log2e -> e = 2^acc. C/D layout:
    // col = lane&15, row = (lane>>4)*4 + reg.
    const int rowBase = bi * 64;
    const int colBase = bj * 64;
    const int rq = h * 4;
    float colAcc[4] = {0.0f, 0.0f, 0.0f, 0.0f};
#pragma unroll
    for (int i = 0; i < 4; ++i) {
      const int rbase = rowBase + i * 16 + rq;
      float rs[4] = {0.0f, 0.0f, 0.0f, 0.0f};
#pragma unroll
      for (int j = 0; j < 4; ++j) {
        fp32x4 v = acc[i][j];
#pragma unroll
        for (int rg = 0; rg < 4; ++rg) {
          float e = __builtin_amdgcn_exp2f(v[rg]);
          if (diag && (rbase + rg) == (colBase + j * 16 + fr))
            e = 0.0f;  // exclude exact diagonal
          rs[rg] += e;
          colAcc[j] += e;
        }
      }
#pragma unroll
      for (int rg = 0; rg < 4; ++rg) {
        float s = rs[rg];
        s += __shfl_xor(s, 1);
        s += __shfl_xor(s, 2);
        s += __shfl_xor(s, 4);
        s += __shfl_xor(s, 8);
        if (fr == 0) atomicAdd(&den[rbase + rg], s);
      }
    }
    if (!diag) {
#pragma unroll
      for (int j = 0; j < 4; ++j) {
        float c = colAcc[j];
        c += __shfl_xor(c, 16);
        c += __shfl_xor(c, 32);
        if (h == 0) atomicAdd(&den[colBase + j * 16 + fr], c);
      }
    }

    // positives exist ONLY when bj == bi + BS/64 (64 of 8256 tiles)
    if (bj == bi + (BS / 64)) {
      float posPart = 0.0f;
#pragma unroll
      for (int i = 0; i < 4; ++i)
#pragma unroll
        for (int j = 0; j < 4; ++j) {
          fp32x4 v = acc[i][j];
#pragma unroll
          for (int rg = 0; rg < 4; ++rg)
            if (j * 16 + fr == i * 16 + rq + rg) posPart += v[rg] * LN2;
        }
      posPart += __shfl_xor(posPart, 1);
      posPart += __shfl_xor(posPart, 2);
      posPart += __shfl_xor(posPart, 4);
      posPart += __shfl_xor(posPart, 8);
      posPart += __shfl_xor(posPart, 16);
      posPart += __shfl_xor(posPart, 32);
      if (lane == 0) atomicAdd(posAcc, posPart);  // upper copy; doubled later
    }

    // advance; reload A band only when the row band changes
    ++bj;
    if (bj == NB64) {
      ++bi;
      bj = bi;
      if (t + 1 < t1) loadA(bi);
    }
  }

  // ---- fence-free tail (no buffer_wbl2/inv: that was +15-19us, R8->R9) --
  // each wave drains its own atomics, THEN the block barrier, THEN publish.
  asm volatile("s_waitcnt vmcnt(0)" ::: "memory");
  __syncthreads();
  if (tid == 0) {
    // hierarchical publish: 8 padded group counters then a master counter
    const int g = (int)(blockIdx.x & 7);
    int last = 0;
    if (__hip_atomic_fetch_add(&ctrs[32 + g * 32], 1, __ATOMIC_RELAXED,
                               __HIP_MEMORY_SCOPE_AGENT) == NPBLK / 8 - 1)
      last = (__hip_atomic_fetch_add(&ctrs[0], 1, __ATOMIC_RELAXED,
                                     __HIP_MEMORY_SCOPE_AGENT) == 7);
    lastFlag = last;
  }
  __syncthreads();
  if (lastFlag) {
    // batched: all 32 per-thread agent-scope loads in flight before use
    float v[32];
#pragma unroll
    for (int io = 0; io < 32; ++io)
      v[io] = __hip_atomic_load(&den[tid + io * NTHR], __ATOMIC_RELAXED,
                                __HIP_MEMORY_SCOPE_AGENT);
    float s = 0.0f;
#pragma unroll
    for (int io = 0; io < 32; ++io)
      s += __builtin_amdgcn_logf(v[io]);  // log2; *ln2 once at the end
#pragma unroll
    for (int off = 1; off < 64; off <<= 1) s += __shfl_xor(s, off);
    if (lane == 0) redbuf[wave] = s;
    __syncthreads();
    if (tid == 0) {
      const float tot =
          (redbuf[0] + redbuf[1] + redbuf[2] + redbuf[3]) * LN2;  // -> ln
      const float pos = __hip_atomic_load(posAcc, __ATOMIC_RELAXED,
                                          __HIP_MEMORY_SCOPE_AGENT);
      // each unordered positive pair was counted once -> double it
      out[0] = (tot - 2.0f * pos) * (1.0f / (float)NROW);
    }
  }
}

extern "C" void kernel_launch(void* const* d_in, const int* in_sizes, int n_in,
                              void* d_out, int out_size, void* d_ws, size_t ws_size,
                              hipStream_t stream) {
  const float* zi = (const float*)d_in[0];
  const float* zj = (const float*)d_in[1];
  float* out = (float*)d_out;

  u8* An = (u8*)d_ws;                                      // 4 MB packed fp8
  float* den = (float*)((char*)d_ws + (size_t)NROW * D);   // 8192 fp32
  float* posAcc = den + NROW;                              // 1 fp32
  int* ctrs = (int*)(posAcc + 1);                          // 288 ints (padded)

  normalize_k<<<NROW / 4, 256, 0, stream>>>(zi, zj, An, den, posAcc, ctrs);
  gemm_expsum<<<NPBLK, NTHR, 0, stream>>>(An, den, posAcc, ctrs, out);
}